// Round 2
// baseline (2079.380 us; speedup 1.0000x reference)
//
#include <hip/hip_runtime.h>
#include <hip/hip_bf16.h>

#define H 4096
#define MOE_I 1024
#define SH_I 4096
#define NE 16
#define T_TOK 4096
#define NPAIR 8192

using bf16x8 = __attribute__((ext_vector_type(8))) short;
using f32x4  = __attribute__((ext_vector_type(4))) float;

__device__ __forceinline__ unsigned short f2bf(float f) {
    unsigned int x = __float_as_uint(f);
    x += 0x7fffu + ((x >> 16) & 1u);   // round-to-nearest-even
    return (unsigned short)(x >> 16);
}
__device__ __forceinline__ float bf2f(unsigned short u) {
    return __uint_as_float(((unsigned int)u) << 16);
}
// packed fp32x2 -> bf16x2 (RNE), single VALU op
__device__ __forceinline__ unsigned int cvtpk(float lo, float hi) {
    unsigned int r;
    asm("v_cvt_pk_bf16_f32 %0, %1, %2" : "=v"(r) : "v"(lo), "v"(hi));
    return r;
}

__device__ __forceinline__ void gld_lds16(const void* g, void* l) {
    __builtin_amdgcn_global_load_lds(
        (const __attribute__((address_space(1))) void*)g,
        (__attribute__((address_space(3))) void*)l, 16, 0, 0);
}

// ---------------- cast fp32 -> bf16 (x only) ----------------
__global__ __launch_bounds__(256)
void cast_kernel(const float4* __restrict__ src, ushort4* __restrict__ dst, int n4) {
    int i = blockIdx.x * 256 + threadIdx.x;
    if (i < n4) {
        float4 f = src[i];
        ushort4 o;
        o.x = f2bf(f.x); o.y = f2bf(f.y); o.z = f2bf(f.z); o.w = f2bf(f.w);
        dst[i] = o;
    }
}

// ---------------- router: logits -> top2 -> weights + histogram ----------------
__global__ __launch_bounds__(256)
void router_kernel(const float* __restrict__ x, const float* __restrict__ gw,
                   int* __restrict__ topk_id, float* __restrict__ topk_w,
                   int* __restrict__ counts) {
    int t = blockIdx.x;
    const float* xr = x + (size_t)t * H;
    __shared__ float lg[NE];
    int tid = threadIdx.x, w = tid >> 6, lane = tid & 63;
#pragma unroll
    for (int i = 0; i < 4; i++) {
        int e = w * 4 + i;
        const float* g = gw + (size_t)e * H;
        float s = 0.f;
        for (int k = lane; k < H; k += 64) s += xr[k] * g[k];
#pragma unroll
        for (int m = 32; m > 0; m >>= 1) s += __shfl_xor(s, m, 64);
        if (lane == 0) lg[e] = s;
    }
    __syncthreads();
    if (tid == 0) {
        int e0 = 0; float l0 = lg[0];
        for (int e = 1; e < NE; e++) if (lg[e] > l0) { l0 = lg[e]; e0 = e; }
        int e1 = -1; float l1 = -1e30f;
        for (int e = 0; e < NE; e++) if (e != e0 && lg[e] > l1) { l1 = lg[e]; e1 = e; }
        float w1 = 1.f / (1.f + __expf(l0 - l1));
        topk_id[2*t] = e0; topk_id[2*t+1] = e1;
        topk_w[2*t] = 1.f - w1; topk_w[2*t+1] = w1;
        atomicAdd(&counts[e0], 1); atomicAdd(&counts[e1], 1);
    }
}

__global__ void scan16(const int* __restrict__ counts, int* __restrict__ offsets,
                       int* __restrict__ cursor) {
    if (threadIdx.x == 0 && blockIdx.x == 0) {
        int s = 0;
        for (int e = 0; e < NE; e++) { offsets[e] = s; cursor[e] = s; s += counts[e]; }
        offsets[NE] = s;
    }
}

__global__ __launch_bounds__(256)
void assign_kernel(const int* __restrict__ topk_id, const float* __restrict__ topk_w,
                   int* __restrict__ cursor, int* __restrict__ perm_tok,
                   float* __restrict__ perm_w) {
    int t = blockIdx.x * blockDim.x + threadIdx.x;
    if (t >= T_TOK) return;
    for (int k = 0; k < 2; k++) {
        int e = topk_id[2*t+k];
        int pos = atomicAdd(&cursor[e], 1);
        perm_tok[pos] = t;
        perm_w[pos] = topk_w[2*t+k];
    }
}

// ---------------- 256x256 MFMA GEMM, 8-phase pipelined, C = A(bf16) @ B(fp32->bf16)^T --
// 512 threads = 8 waves (2M x 4N), BK=64 (2 k-halves of 32), 128 KiB LDS (2 bufs).
// A staged via global_load_lds (bf16, pre-swizzled source). B read fp32 from HBM,
// reg-staged, cvt_pk to bf16, ds_write to swizzled LDS (same layout as A).
// Per-buffer LDS: A [kh][256][32]bf16 at +0, B same at +32768. swizzle: slot ^= (row>>1)&3.
// MODE 0: gate_up shared: B rows interleaved (col 2j=gate j, 2j+1=up j), epilogue fuses
//         silu(g)*u -> bf16 act store (ldc = N/2).
// MODE 1: plain fp32 store.
// MODE 2: expert gate_up: A rows gathered via perm_tok; fused swiglu store at off+row.
// MODE 3: expert down: A rows = off+row, epilogue atomicAdd(Cf[perm_tok], perm_w*v).
template<int MODE>
__global__ __launch_bounds__(512, 2)
void gemm8(const unsigned short* __restrict__ A0,
           const float* __restrict__ B0f,
           unsigned short* __restrict__ Cb, float* __restrict__ Cf,
           const int* __restrict__ offsets, const int* __restrict__ perm_tok,
           const float* __restrict__ perm_w,
           int K, int N, int M, int ldc) {
    extern __shared__ char smem[];
    int e = 0, off = 0, cnt = M;
    if constexpr (MODE >= 2) { e = blockIdx.z; off = offsets[e]; cnt = offsets[e + 1] - off; }
    const int m0 = blockIdx.y * 256, n0 = blockIdx.x * 256;
    if (m0 >= cnt) return;
    const float* Bp = B0f + (size_t)e * N * K;

    const int tid = threadIdx.x, w = tid >> 6, lane = tid & 63;
    const int wr = w >> 2, wc = w & 3;          // wave tile: 128 rows x 64 cols
    const int quad = lane >> 4, r16 = lane & 15;

    // ---- A staging: gld_lds, pre-swizzled global source, linear LDS dest ----
    const unsigned short* srcA[2][2];
    int dstA[2][2];
#pragma unroll
    for (int kh = 0; kh < 2; kh++)
#pragma unroll
        for (int j = 0; j < 2; j++) {
            int D  = (j * 8 + w) * 1024 + lane * 16;   // linear byte dest in 16KB half
            int r  = D >> 6;                           // tile row 0..255
            int sl = (D >> 4) & 3;
            int sg = sl ^ ((r >> 1) & 3);              // swizzled source slot
            int ra = m0 + r; if (ra > cnt - 1) ra = cnt - 1;
            int rs;
            if constexpr (MODE == 2)      rs = perm_tok[off + ra];
            else if constexpr (MODE == 3) rs = off + ra;
            else                          rs = ra;
            srcA[kh][j] = A0 + (size_t)rs * K + kh * 32 + sg * 8;
            dstA[kh][j] = kh * 16384 + (j * 8 + w) * 1024;
        }

    // ---- B staging: fp32 reg loads. round i: row = i*stride_r + (tid>>4), k = (tid&15)*4
    const int r_t  = tid >> 4;           // 0..31
    const int kcol = (tid & 15) * 4;     // float index in 64-wide K window
    const float* bsrc;
    size_t rstride;                      // floats per round-step
    if constexpr (MODE == 0 || MODE == 2) {
        int n = n0 + r_t;
        int sr = (n >> 1) + (n & 1) * (N >> 1);   // interleave: even=gate, odd=up
        bsrc = Bp + (size_t)sr * K + kcol;
        rstride = (size_t)16 * K;                  // row parity fixed per thread
    } else {
        bsrc = Bp + (size_t)(n0 + r_t) * K + kcol;
        rstride = (size_t)32 * K;
    }
    // B LDS write base (b64 per round, +2048B per round; swizzle const per thread)
    const int bw0 = 32768 + (kcol >> 5) * 16384 + r_t * 64
                  + ((((kcol & 31) >> 3) ^ ((r_t >> 1) & 3)) * 16) + (kcol & 7) * 2;

    // ---- ds_read addressing (swizzled) ----
    const int swz  = (quad ^ ((r16 >> 1) & 3)) * 16;
    const int aoff = (wr * 128 + r16) * 64 + swz;
    const int boff = 32768 + (wc * 64 + r16) * 64 + swz;

    f32x4 acc[8][4];
#pragma unroll
    for (int i = 0; i < 8; i++)
#pragma unroll
        for (int j = 0; j < 4; j++) acc[i][j] = (f32x4){0.f, 0.f, 0.f, 0.f};

    const int nt = K >> 6;

    // ---- prologue: stage tile 0 into buf0. vm issue order: AK0(2), Bld(8), AK1(2) ----
    gld_lds16(srcA[0][0], smem + dstA[0][0]);
    gld_lds16(srcA[0][1], smem + dstA[0][1]);
    {
        float4 b0[8];
#pragma unroll
        for (int i = 0; i < 8; i++) b0[i] = *(const float4*)(bsrc + (size_t)i * rstride);
        gld_lds16(srcA[1][0], smem + dstA[1][0]);
        gld_lds16(srcA[1][1], smem + dstA[1][1]);
#pragma unroll
        for (int i = 0; i < 8; i++) {          // compiler inserts vmcnt wait before cvt
            uint2 u2; u2.x = cvtpk(b0[i].x, b0[i].y); u2.y = cvtpk(b0[i].z, b0[i].w);
            *(uint2*)(smem + bw0 + i * 2048) = u2;
        }
    }
    {
        int adv0 = (nt > 1) ? 64 : 0;
#pragma unroll
        for (int kh = 0; kh < 2; kh++)
#pragma unroll
            for (int j = 0; j < 2; j++) srcA[kh][j] += adv0;
        bsrc += adv0;
    }

    for (int t = 0; t < nt; t++) {
        char* sb = smem + (t & 1) * 65536;          // compute buffer
        char* so = smem + ((t + 1) & 1) * 65536;    // stage target (tile t+1)
        const int advA = (t + 2 < nt) ? 64 : 0;
        bf16x8 av[4], bv[4];
        float4 bld[8];

        // ===== boundary: drain own ds_writes, sync; AK0(t)/B(t) now visible =====
        asm volatile("s_waitcnt lgkmcnt(0)" ::: "memory");
        __builtin_amdgcn_s_barrier();
        // ----- P1: issue AK0(t+1); compute ks=0, rows m0-3 -----
        gld_lds16(srcA[0][0], so + dstA[0][0]);
        gld_lds16(srcA[0][1], so + dstA[0][1]);
        srcA[0][0] += advA; srcA[0][1] += advA;
#pragma unroll
        for (int mi = 0; mi < 4; mi++) av[mi] = *(const bf16x8*)(sb + mi * 1024 + aoff);
#pragma unroll
        for (int ni = 0; ni < 4; ni++) bv[ni] = *(const bf16x8*)(sb + ni * 1024 + boff);
        __builtin_amdgcn_s_setprio(1);
#pragma unroll
        for (int mi = 0; mi < 4; mi++)
#pragma unroll
            for (int ni = 0; ni < 4; ni++)
                acc[mi][ni] = __builtin_amdgcn_mfma_f32_16x16x32_bf16(
                    av[mi], bv[ni], acc[mi][ni], 0, 0, 0);
        __builtin_amdgcn_s_setprio(0);
        // ----- P2: issue B fp32 loads (t+1), pinned; compute ks=0, rows m4-7 -----
        __builtin_amdgcn_sched_barrier(0);
#pragma unroll
        for (int i = 0; i < 8; i++) bld[i] = *(const float4*)(bsrc + (size_t)i * rstride);
        __builtin_amdgcn_sched_barrier(0);
#pragma unroll
        for (int mi = 0; mi < 4; mi++) av[mi] = *(const bf16x8*)(sb + (mi + 4) * 1024 + aoff);
        __builtin_amdgcn_s_setprio(1);
#pragma unroll
        for (int mi = 0; mi < 4; mi++)
#pragma unroll
            for (int ni = 0; ni < 4; ni++)
                acc[mi + 4][ni] = __builtin_amdgcn_mfma_f32_16x16x32_bf16(
                    av[mi], bv[ni], acc[mi + 4][ni], 0, 0, 0);
        __builtin_amdgcn_s_setprio(0);

        // ===== mid: own AK1(t) landed (10 younger vm ops stay in flight) =====
        asm volatile("s_waitcnt vmcnt(10)" ::: "memory");
        __builtin_amdgcn_s_barrier();
        // ----- P3: issue AK1(t+1); compute ks=1, rows m0-3 -----
        gld_lds16(srcA[1][0], so + dstA[1][0]);
        gld_lds16(srcA[1][1], so + dstA[1][1]);
        srcA[1][0] += advA; srcA[1][1] += advA;
#pragma unroll
        for (int mi = 0; mi < 4; mi++) av[mi] = *(const bf16x8*)(sb + 16384 + mi * 1024 + aoff);
#pragma unroll
        for (int ni = 0; ni < 4; ni++) bv[ni] = *(const bf16x8*)(sb + 16384 + ni * 1024 + boff);
        __builtin_amdgcn_s_setprio(1);
#pragma unroll
        for (int mi = 0; mi < 4; mi++)
#pragma unroll
            for (int ni = 0; ni < 4; ni++)
                acc[mi][ni] = __builtin_amdgcn_mfma_f32_16x16x32_bf16(
                    av[mi], bv[ni], acc[mi][ni], 0, 0, 0);
        __builtin_amdgcn_s_setprio(0);
        // ----- P4: cvt+ds_write B(t+1) -> so; compute ks=1, rows m4-7 -----
#pragma unroll
        for (int i = 0; i < 8; i++) {          // compiler waits bld (forces AK0(t+1) too)
            uint2 u2; u2.x = cvtpk(bld[i].x, bld[i].y); u2.y = cvtpk(bld[i].z, bld[i].w);
            *(uint2*)(so + bw0 + i * 2048) = u2;
        }
        bsrc += (t + 2 < nt) ? 64 : 0;
#pragma unroll
        for (int mi = 0; mi < 4; mi++) av[mi] = *(const bf16x8*)(sb + 16384 + (mi + 4) * 1024 + aoff);
        __builtin_amdgcn_s_setprio(1);
#pragma unroll
        for (int mi = 0; mi < 4; mi++)
#pragma unroll
            for (int ni = 0; ni < 4; ni++)
                acc[mi + 4][ni] = __builtin_amdgcn_mfma_f32_16x16x32_bf16(
                    av[mi], bv[ni], acc[mi + 4][ni], 0, 0, 0);
        __builtin_amdgcn_s_setprio(0);
    }

    // drain all LDS-DMA before epilogue / exit
    asm volatile("s_waitcnt vmcnt(0)" ::: "memory");

    // ---- epilogue: C/D layout col = lane&15, row = quad*4 + reg ----
    const int rowlim = cnt - m0;
    if constexpr (MODE == 0 || MODE == 2) {
        // fused SwiGLU: col 2j = gate_j, col 2j+1 = up_j; pair via shfl_xor(1)
#pragma unroll
        for (int mi = 0; mi < 8; mi++) {
#pragma unroll
            for (int rr = 0; rr < 4; rr++) {
                int r = wr * 128 + mi * 16 + quad * 4 + rr;
#pragma unroll
                for (int ni = 0; ni < 4; ni++) {
                    float g = acc[mi][ni][rr];
                    float u = __shfl_xor(g, 1, 64);
                    if (((r16 & 1) == 0) && (r < rowlim)) {
                        float a = (g / (1.f + __expf(-g))) * u;
                        size_t row = (MODE == 0) ? (size_t)(m0 + r) : (size_t)(off + m0 + r);
                        int colh = (n0 >> 1) + wc * 32 + ni * 8 + (r16 >> 1);
                        Cb[row * ldc + colh] = f2bf(a);
                    }
                }
            }
        }
    } else {
#pragma unroll
        for (int mi = 0; mi < 8; mi++) {
#pragma unroll
            for (int rr = 0; rr < 4; rr++) {
                int r = wr * 128 + mi * 16 + quad * 4 + rr;
                if (r < rowlim) {
                    int tok = 0; float wt = 0.f;
                    if constexpr (MODE == 3) {
                        tok = perm_tok[off + m0 + r];
                        wt  = perm_w[off + m0 + r];
                    }
#pragma unroll
                    for (int ni = 0; ni < 4; ni++) {
                        int col = n0 + wc * 64 + ni * 16 + r16;
                        float v = acc[mi][ni][rr];
                        if constexpr (MODE == 1)
                            Cf[(size_t)(m0 + r) * ldc + col] = v;
                        else
                            atomicAdd(&Cf[(size_t)tok * ldc + col], wt * v);
                    }
                }
            }
        }
    }
}

extern "C" void kernel_launch(void* const* d_in, const int* in_sizes, int n_in,
                              void* d_out, int out_size, void* d_ws, size_t ws_size,
                              hipStream_t stream) {
    const float* x         = (const float*)d_in[0];
    const float* gate_w    = (const float*)d_in[1];
    const float* w_gate_up = (const float*)d_in[2];
    const float* w_down    = (const float*)d_in[3];
    const float* s_wgu     = (const float*)d_in[4];
    const float* s_wd      = (const float*)d_in[5];
    float* out = (float*)d_out;

    char* p = (char*)d_ws;
    auto alloc = [&](size_t bytes) {
        char* q = p;
        p += (bytes + 255) & ~(size_t)255;
        return q;
    };
    unsigned short* x_bf   = (unsigned short*)alloc((size_t)T_TOK * H * 2);
    unsigned short* act_s  = (unsigned short*)alloc((size_t)T_TOK * SH_I * 2);
    unsigned short* act_e  = (unsigned short*)alloc((size_t)NPAIR * MOE_I * 2);
    int*   topk_id  = (int*)alloc(T_TOK * 2 * 4);
    float* topk_w   = (float*)alloc(T_TOK * 2 * 4);
    int*   counts   = (int*)alloc(NE * 4);
    int*   offsets  = (int*)alloc((NE + 1) * 4);
    int*   cursor   = (int*)alloc(NE * 4);
    int*   perm_tok = (int*)alloc(NPAIR * 4);
    float* perm_w   = (float*)alloc(NPAIR * 4);

    // counts/offsets/cursor are three consecutive 256B-aligned slots
    hipMemsetAsync(counts, 0, 768, stream);

    const int SHMEM = 131072;
    static int attr_done = 0;
    if (!attr_done) {
        hipFuncSetAttribute((const void*)gemm8<0>, hipFuncAttributeMaxDynamicSharedMemorySize, SHMEM);
        hipFuncSetAttribute((const void*)gemm8<1>, hipFuncAttributeMaxDynamicSharedMemorySize, SHMEM);
        hipFuncSetAttribute((const void*)gemm8<2>, hipFuncAttributeMaxDynamicSharedMemorySize, SHMEM);
        hipFuncSetAttribute((const void*)gemm8<3>, hipFuncAttributeMaxDynamicSharedMemorySize, SHMEM);
        attr_done = 1;
    }

    {
        int n4 = (int)((size_t)T_TOK * H / 4);
        cast_kernel<<<(n4 + 255) / 256, 256, 0, stream>>>((const float4*)x, (ushort4*)x_bf, n4);
    }

    router_kernel<<<T_TOK, 256, 0, stream>>>(x, gate_w, topk_id, topk_w, counts);
    scan16<<<1, 64, 0, stream>>>(counts, offsets, cursor);
    assign_kernel<<<16, 256, 0, stream>>>(topk_id, topk_w, cursor, perm_tok, perm_w);

    // shared gate_up + fused SwiGLU: x_bf @ s_wgu(fp32)^T -> act_s [T, SH_I] bf16
    gemm8<0><<<dim3(2 * SH_I / 256, T_TOK / 256, 1), 512, SHMEM, stream>>>(
        x_bf, s_wgu, act_s, nullptr, nullptr, nullptr, nullptr, H, 2 * SH_I, T_TOK, SH_I);
    // shared down: act_s @ s_wd(fp32)^T -> out (plain fp32 store, covers all elements)
    gemm8<1><<<dim3(H / 256, T_TOK / 256, 1), 512, SHMEM, stream>>>(
        act_s, s_wd, nullptr, out, nullptr, nullptr, nullptr, SH_I, H, T_TOK, H);

    // expert gate_up (gathered A) + fused SwiGLU -> act_e [NPAIR, MOE_I] bf16
    gemm8<2><<<dim3(2 * MOE_I / 256, T_TOK / 256, NE), 512, SHMEM, stream>>>(
        x_bf, w_gate_up, act_e, nullptr, offsets, perm_tok, nullptr, H, 2 * MOE_I, 0, MOE_I);
    // expert down: scatter-atomicAdd onto out (after shared down)
    gemm8<3><<<dim3(H / 256, T_TOK / 256, NE), 512, SHMEM, stream>>>(
        act_e, w_down, nullptr, out, offsets, perm_tok, perm_w, MOE_I, H, 0, H);
}